// Round 1
// baseline (484.017 us; speedup 1.0000x reference)
//
#include <hip/hip_runtime.h>

#define NC 8192
#define NT 4096
#define NLAGS 103        // lag index 0..102 ; actual lag = idx - 51
#define WS_STRIDE 104    // padded row stride in scratch
#define D1SZ 4208        // 51 zeros + 4096 data + 61 zeros (16B-aligned tail)
#define LPW 28           // lags per wave (4 waves x 28 = 112 >= 103)
#define CK 16            // k-chunk per lane
#define XBASE (NC*NLAGS)

// ---------------- Kernel 1: per-channel cross-correlation ----------------
// One block (256 threads = 4 waves) per channel.
// d1s[i] = data1[i-51] zero-padded => R[L] = sum_k d1s[k+L]*d2[k], L=0..102.
// Wave w computes lags [w*28, w*28+28) (garbage lags >=103 discarded).
// Each lane: k-chunk of 16 (d2 in regs), 44-float sliding d1 window in regs:
// 448 FMAs per 15 ds_read_b128 -> VALU-bound, not LDS-bound.
__global__ __launch_bounds__(256, 4)
void xcorr_kernel(const float* __restrict__ g1, const float* __restrict__ g2,
                  float* __restrict__ ws) {
    __shared__ float smem[D1SZ + NT];   // d1s | d2s ; reused for reduction
    float* d1s = smem;
    float* d2s = smem + D1SZ;
    const int c   = blockIdx.x;
    const int tid = threadIdx.x;
    const float* r1 = g1 + (size_t)c * NT;
    const float* r2 = g2 + (size_t)c * NT;

    // stage data1 (scalar, lane-consecutive => conflict-free despite +51 skew)
    #pragma unroll
    for (int i = 0; i < NT/256; ++i) d1s[51 + tid + 256*i] = r1[tid + 256*i];
    if (tid < 51) d1s[tid] = 0.f;                 // left zero pad
    if (tid < 61) d1s[51 + NT + tid] = 0.f;       // right zero pad (to 4208)
    {   // stage data2 vectorized (16B aligned all the way)
        const float4* r24 = (const float4*)r2;
        float4* s24 = (float4*)d2s;
        #pragma unroll
        for (int i = 0; i < NT/4/256; ++i) s24[tid + 256*i] = r24[tid + 256*i];
    }
    __syncthreads();

    const int wv   = tid >> 6;
    const int lane = tid & 63;
    const int l0   = wv * LPW;

    float acc[LPW];
    #pragma unroll
    for (int l = 0; l < LPW; ++l) acc[l] = 0.f;

    #pragma unroll
    for (int it = 0; it < NT/(64*CK); ++it) {     // 4 k-iterations
        const int k0 = it*(64*CK) + lane*CK;
        float b[CK];
        #pragma unroll
        for (int t = 0; t < CK/4; ++t) {
            float4 v = *(const float4*)&d2s[k0 + 4*t];
            b[4*t]=v.x; b[4*t+1]=v.y; b[4*t+2]=v.z; b[4*t+3]=v.w;
        }
        float wd[LPW + CK];                       // 44-float d1 window
        #pragma unroll
        for (int t = 0; t < (LPW+CK)/4; ++t) {    // 11 ds_read_b128 (4-aligned)
            float4 v = *(const float4*)&d1s[k0 + l0 + 4*t];
            wd[4*t]=v.x; wd[4*t+1]=v.y; wd[4*t+2]=v.z; wd[4*t+3]=v.w;
        }
        #pragma unroll
        for (int j = 0; j < CK; ++j)
            #pragma unroll
            for (int l = 0; l < LPW; ++l)
                acc[l] = fmaf(wd[l+j], b[j], acc[l]);
    }

    // ---- intra-wave reduction via LDS (reuse staging area after barrier) ----
    __syncthreads();
    float* red = smem + wv * (64*LPW);            // per-wave 1792-float segment
    #pragma unroll
    for (int t = 0; t < LPW/4; ++t)
        *(float4*)&red[lane*LPW + 4*t] =
            make_float4(acc[4*t], acc[4*t+1], acc[4*t+2], acc[4*t+3]);
    // wave-synchronous: same-wave DS ops complete in order, no barrier needed
    float sum = 0.f;
    const int lcol = lane & 31;                   // lag column within chunk
    const int rb   = lane & 32;                   // row half (2-way bank alias = free)
    #pragma unroll
    for (int r = 0; r < 32; ++r) sum += red[(rb + r)*LPW + lcol];
    sum += __shfl_down(sum, 32);                  // combine the two row-halves
    const int L = l0 + lcol;
    if (lane < LPW && L < NLAGS)
        ws[(size_t)c * WS_STRIDE + L] = sum;
}

// -------- Kernel 2: moving average across channels + pick max|R| --------
// Block handles 32 channels; needs halo rows c0-10 .. c0+41 (52 rows).
__global__ __launch_bounds__(256, 4)
void ma_pick_kernel(const float* __restrict__ ws, float* __restrict__ out) {
    __shared__ float tile[52*WS_STRIDE];
    __shared__ float matile[32*WS_STRIDE];
    const int tid = threadIdx.x;
    const int c0  = blockIdx.x * 32;

    for (int i = tid; i < 52*WS_STRIDE; i += 256) {
        int r   = i / WS_STRIDE;
        int col = i - r*WS_STRIDE;
        int g   = c0 - 10 + r;
        float v = 0.f;
        if (g >= 0 && g < NC && col < NLAGS) v = ws[(size_t)g*WS_STRIDE + col];
        tile[i] = v;
    }
    __syncthreads();

    {   // rolling 20-channel window sum; thread = one lag, 16 channels
        const int l = tid & 127;
        const int h = tid >> 7;
        if (l < NLAGS) {
            const int cc0 = h * 16;
            float s = 0.f;
            #pragma unroll
            for (int r = 0; r < 20; ++r) s += tile[(cc0 + r)*WS_STRIDE + l];
            #pragma unroll 1
            for (int cc = cc0; cc < cc0 + 16; ++cc) {
                float ma = s / 20.0f;
                matile[cc*WS_STRIDE + l] = ma;
                out[(size_t)(c0 + cc)*NLAGS + l] = ma;   // coalesced across l
                s += tile[(cc + 20)*WS_STRIDE + l] - tile[cc*WS_STRIDE + l];
            }
        }
    }
    __syncthreads();

    // per-channel argmax|R| (first-index tie-break, matches jnp.argmax), max, min
    const int wv = tid >> 6, lane = tid & 63;
    #pragma unroll 1
    for (int s8 = 0; s8 < 8; ++s8) {
        const int cc = wv*8 + s8;
        float v1 = matile[cc*WS_STRIDE + lane];
        float a1 = fabsf(v1);
        int   i1 = lane;
        float vmx = v1, vmn = v1;
        if (lane < NLAGS - 64) {                  // second element: l = lane+64
            float v2 = matile[cc*WS_STRIDE + 64 + lane];
            float a2 = fabsf(v2);
            vmx = fmaxf(vmx, v2); vmn = fminf(vmn, v2);
            if (a2 > a1) { a1 = a2; i1 = 64 + lane; v1 = v2; }
        }
        #pragma unroll
        for (int d = 32; d >= 1; d >>= 1) {
            float oa  = __shfl_xor(a1, d);
            int   oi  = __shfl_xor(i1, d);
            float ov  = __shfl_xor(v1, d);
            float omx = __shfl_xor(vmx, d);
            float omn = __shfl_xor(vmn, d);
            vmx = fmaxf(vmx, omx);
            vmn = fminf(vmn, omn);
            if (oa > a1 || (oa == a1 && oi < i1)) { a1 = oa; i1 = oi; v1 = ov; }
        }
        if (lane == 0) {
            const int c = c0 + cc;
            out[XBASE + c]        = v1;                          // vmain
            out[XBASE + NC + c]   = (v1 >= 0.f) ? vmn : vmx;     // vside
            out[XBASE + 2*NC + c] = (float)(i1 - 51) * 0.01f;    // tmax
        }
    }
}

extern "C" void kernel_launch(void* const* d_in, const int* in_sizes, int n_in,
                              void* d_out, int out_size, void* d_ws, size_t ws_size,
                              hipStream_t stream) {
    const float* g1 = (const float*)d_in[0];
    const float* g2 = (const float*)d_in[1];
    // d_in[2]/d_in[3] (event1/event2) are unused by the reference.
    float* out = (float*)d_out;
    float* ws  = (float*)d_ws;   // needs 8192*104*4 = 3.4 MB scratch

    hipLaunchKernelGGL(xcorr_kernel, dim3(NC), dim3(256), 0, stream, g1, g2, ws);
    hipLaunchKernelGGL(ma_pick_kernel, dim3(NC/32), dim3(256), 0, stream, ws, out);
}

// Round 2
// 318.367 us; speedup vs baseline: 1.5203x; 1.5203x over previous
//
#include <hip/hip_runtime.h>

#define NC 8192
#define NT 4096
#define NLAGS 103        // lag index 0..102 ; actual lag = idx - 51
#define WS_STRIDE 104    // row stride in scratch
#define LPW 28           // lags per wave (4 waves x 28 = 112 >= 103)
#define PADL 51
#define D1LOG 4208       // 51 zeros + 4096 data + 61 zeros (logical)
// Padded LDS layout: 4 pad dwords per 16 -> lane stride 20 dwords (4*odd)
// spreads ds_read_b128 over all banks; reads at x%4==0, x%16 in {0,4,8,12}
// never cross a pad and stay 16B-aligned.
#define PHYS(x) ((x) + (((x) >> 4) << 2))
#define D1P 5260         // PHYS span of 4208 logical
#define D2P 5120         // PHYS span of 4096 logical
#define SMEMF (D1P + D2P)  // 10380 floats = 41.5 KB -> 3 blocks/CU
#define XBASE (NC*NLAGS)

// ---------------- Kernel 1: per-channel cross-correlation ----------------
// One block (256 threads = 4 waves) per channel.
// R[L] = sum_k d1s[k+L]*d2[k], L=0..102, d1s = data1 zero-padded by 51.
// Wave w: lags [28w, 28w+28); lane: k-chunk of 16; 448 FMAs per 15 b128.
__global__ __launch_bounds__(256, 3)
void xcorr_kernel(const float* __restrict__ g1, const float* __restrict__ g2,
                  float* __restrict__ ws) {
    __shared__ __align__(16) float smem[SMEMF];
    float* d1s = smem;
    float* d2s = smem + D1P;
    const int c   = blockIdx.x;
    const int tid = threadIdx.x;
    const float4* r14 = (const float4*)(g1 + (size_t)c * NT);
    const float4* r24 = (const float4*)(g2 + (size_t)c * NT);

    #pragma unroll
    for (int i = 0; i < 4; ++i) {
        float4 v = r14[tid + 256*i];
        int x = PADL + 4*(tid + 256*i);          // x%4==3: scalar stores
        d1s[PHYS(x)]   = v.x;
        d1s[PHYS(x+1)] = v.y;
        d1s[PHYS(x+2)] = v.z;
        d1s[PHYS(x+3)] = v.w;
        float4 u = r24[tid + 256*i];
        int y = 4*(tid + 256*i);                 // y%4==0: vector store ok
        *(float4*)&d2s[PHYS(y)] = u;
    }
    if (tid < PADL) d1s[PHYS(tid)] = 0.f;                 // left zero pad
    if (tid < 61)   d1s[PHYS(PADL + NT + tid)] = 0.f;     // right zero pad
    __syncthreads();

    const int wv   = tid >> 6;
    const int lane = tid & 63;
    const int l0   = wv * LPW;                   // {0,28,56,84}: %4==0

    float acc[LPW];
    #pragma unroll
    for (int l = 0; l < LPW; ++l) acc[l] = 0.f;

    #pragma unroll 1
    for (int it = 0; it < 4; ++it) {             // 4 k-blocks of 1024
        const int k0 = it*1024 + lane*16;
        float b[16];
        #pragma unroll
        for (int t = 0; t < 4; ++t) {
            int y = k0 + 4*t;
            float4 v = *(const float4*)&d2s[PHYS(y)];
            b[4*t]=v.x; b[4*t+1]=v.y; b[4*t+2]=v.z; b[4*t+3]=v.w;
        }
        float w[LPW + 16];                       // 44-dword sliding window
        #pragma unroll
        for (int t = 0; t < 11; ++t) {
            int x = k0 + l0 + 4*t;
            float4 v = *(const float4*)&d1s[PHYS(x)];
            w[4*t]=v.x; w[4*t+1]=v.y; w[4*t+2]=v.z; w[4*t+3]=v.w;
        }
        #pragma unroll
        for (int j = 0; j < 16; ++j)
            #pragma unroll
            for (int l = 0; l < LPW; ++l)
                acc[l] = fmaf(w[l+j], b[j], acc[l]);
    }

    // ---- reduction across the 64 lanes' partial sums (reuse smem) ----
    __syncthreads();
    float* red = smem + wv * (64*29);            // stride 29 (odd): no conflicts
    #pragma unroll
    for (int l = 0; l < LPW; ++l) red[lane*29 + l] = acc[l];
    // same-wave DS ops complete in order; no barrier needed
    float sum = 0.f;
    const int lcol = lane & 31;
    const int rb   = lane & 32;                  // 2-way row-half alias = free
    #pragma unroll
    for (int r = 0; r < 32; ++r) sum += red[(rb + r)*29 + lcol];
    sum += __shfl_down(sum, 32);
    const int L = l0 + lcol;
    if (lane < LPW && L < NLAGS)
        ws[(size_t)c * WS_STRIDE + L] = sum;
}

// -------- Kernel 2: moving average across channels + pick max|R| --------
#define TS 112   // tile stride (16*7: rows alias 2-way = free)
__global__ __launch_bounds__(256, 4)
void ma_pick_kernel(const float* __restrict__ ws, float* __restrict__ out) {
    __shared__ float tile[52*TS];
    __shared__ float matile[32*TS];
    const int tid = threadIdx.x;
    const int c0  = blockIdx.x * 32;

    for (int i = tid; i < 52*TS; i += 256) {
        int r   = i / TS;
        int col = i - r*TS;
        int g   = c0 - 10 + r;
        float v = 0.f;
        if (g >= 0 && g < NC && col < NLAGS) v = ws[(size_t)g*WS_STRIDE + col];
        tile[i] = v;
    }
    __syncthreads();

    {   // rolling 20-channel window sum; thread = one lag, 16 channels
        const int l = tid & 127;
        const int h = tid >> 7;
        if (l < NLAGS) {
            const int cc0 = h * 16;
            float s = 0.f;
            #pragma unroll
            for (int r = 0; r < 20; ++r) s += tile[(cc0 + r)*TS + l];
            #pragma unroll 1
            for (int cc = cc0; cc < cc0 + 16; ++cc) {
                float ma = s / 20.0f;
                matile[cc*TS + l] = ma;
                out[(size_t)(c0 + cc)*NLAGS + l] = ma;   // coalesced across l
                s += tile[(cc + 20)*TS + l] - tile[cc*TS + l];
            }
        }
    }
    __syncthreads();

    // per-channel argmax|R| (first-index tie-break), max, min
    const int wv = tid >> 6, lane = tid & 63;
    #pragma unroll 1
    for (int s8 = 0; s8 < 8; ++s8) {
        const int cc = wv*8 + s8;
        float v1 = matile[cc*TS + lane];
        float a1 = fabsf(v1);
        int   i1 = lane;
        float vmx = v1, vmn = v1;
        if (lane < NLAGS - 64) {                 // second element: l = lane+64
            float v2 = matile[cc*TS + 64 + lane];
            float a2 = fabsf(v2);
            vmx = fmaxf(vmx, v2); vmn = fminf(vmn, v2);
            if (a2 > a1) { a1 = a2; i1 = 64 + lane; v1 = v2; }
        }
        #pragma unroll
        for (int d = 32; d >= 1; d >>= 1) {
            float oa  = __shfl_xor(a1, d);
            int   oi  = __shfl_xor(i1, d);
            float ov  = __shfl_xor(v1, d);
            float omx = __shfl_xor(vmx, d);
            float omn = __shfl_xor(vmn, d);
            vmx = fmaxf(vmx, omx);
            vmn = fminf(vmn, omn);
            if (oa > a1 || (oa == a1 && oi < i1)) { a1 = oa; i1 = oi; v1 = ov; }
        }
        if (lane == 0) {
            const int ch = c0 + cc;
            out[XBASE + ch]        = v1;                         // vmain
            out[XBASE + NC + ch]   = (v1 >= 0.f) ? vmn : vmx;    // vside
            out[XBASE + 2*NC + ch] = (float)(i1 - 51) * 0.01f;   // tmax
        }
    }
}

extern "C" void kernel_launch(void* const* d_in, const int* in_sizes, int n_in,
                              void* d_out, int out_size, void* d_ws, size_t ws_size,
                              hipStream_t stream) {
    const float* g1 = (const float*)d_in[0];
    const float* g2 = (const float*)d_in[1];
    float* out = (float*)d_out;
    float* ws  = (float*)d_ws;   // 8192*104*4 = 3.4 MB scratch

    hipLaunchKernelGGL(xcorr_kernel, dim3(NC), dim3(256), 0, stream, g1, g2, ws);
    hipLaunchKernelGGL(ma_pick_kernel, dim3(NC/32), dim3(256), 0, stream, ws, out);
}